// Round 1
// 962.182 us; speedup vs baseline: 1.1785x; 1.1785x over previous
//
#include <hip/hip_runtime.h>
#include <hip/hip_bf16.h>
#include <string.h>

// GNN layer, bf16-MFMA restructuring:
//   AB = nf @ [We1_s | We1_d]      [N,512] bf16  (A|B halves per row)
//   edge_fused (per 128-edge block, feature half per block):
//     C  = ef_tile @ We1_e  (MFMA, K=64) -> LDS (never hits HBM)
//     H[d] += lrelu(A[s]+B[d]+C[e]); H[s] += lrelu(A[d]+B[s]+C[e])
//          H is bf16, accumulated with native global_atomic_pk_add_bf16
//   red = H @ We2 ; hid = lrelu([nf|red]@Wn1) ; out = hid @ Wn2
// All GEMMs: 128x128 tile, 4 waves, mfma_f32_16x16x32_bf16, fp32 accum.
// edge phase: one wave = one edge; lane j = feature pair (2j,2j+1) of the
// 128-feature half -> every wave-level load/atomic touches 256B CONSECUTIVE
// bytes (round-2 lesson: strided per-lane atomics are 4x slower).

using f32x4  = __attribute__((ext_vector_type(4))) float;
using bf16x8 = __attribute__((ext_vector_type(8))) short;

#define LROW 72    // staging LDS row pitch in bf16 units (144 B)
#define CROW 132   // C tile LDS pitch in bf16 units (264 B): conflict-free writes

__device__ __forceinline__ float lrelu(float x) { return x >= 0.f ? x : 0.01f * x; }

__device__ __forceinline__ ushort f2bf(float f) {
    union { float f; unsigned u; } v; v.f = f;
    unsigned u = v.u;
    return (ushort)((u + 0x7fffu + ((u >> 16) & 1u)) >> 16);   // RNE
}
__device__ __forceinline__ float bf2f(ushort u) {
    union { unsigned u; float f; } v; v.u = ((unsigned)u) << 16; return v.f;
}

// native packed bf16 atomic add (gfx942+/gfx950); addr must be 4B-aligned
__device__ __forceinline__ void atomic_pk_add_bf16(void* addr, unsigned val) {
    asm volatile("global_atomic_pk_add_bf16 %0, %1, off" : : "v"(addr), "v"(val) : "memory");
}

// out[M,Nw] = cat(X1[M,K1], X2[M,K2]) @ Wt^T   (Wt is [Nw,K] bf16, n-major)
// M (grid.x*128) must be fully padded; stores guarded by Mstore.
// flags: 1 = lrelu, 2 = bf16 output (else fp32)
__global__ __launch_bounds__(256) void gemm_bf16(
    const ushort* __restrict__ X1, int K1,
    const ushort* __restrict__ X2, int K2,
    const ushort* __restrict__ Wt,
    void* __restrict__ out, int Nw, int Mstore, int flags)
{
    __shared__ ushort Xs[128 * LROW];
    __shared__ ushort Ws[128 * LROW];

    const int K    = K1 + K2;
    const int tid  = threadIdx.x;
    const int lane = tid & 63;
    const int wv   = tid >> 6;
    const int wm   = wv >> 1, wn = wv & 1;
    const int row0 = blockIdx.x * 128;
    const int col0 = blockIdx.y * 128;

    f32x4 acc[4][4] = {};

    for (int k0 = 0; k0 < K; k0 += 64) {
        const ushort* Xsrc; int kloc, ksz;
        if (k0 < K1) { Xsrc = X1; kloc = k0;      ksz = K1; }
        else         { Xsrc = X2; kloc = k0 - K1; ksz = K2; }

        const int r_  = tid >> 3;          // 0..31
        const int kk  = (tid & 7) * 8;     // bf16 offset 0..56
        uint4 xv[4], wvv[4];
        #pragma unroll
        for (int p = 0; p < 4; ++p) {
            int r = p * 32 + r_;
            xv[p]  = *reinterpret_cast<const uint4*>(Xsrc + (size_t)(row0 + r) * ksz + kloc + kk);
            wvv[p] = *reinterpret_cast<const uint4*>(Wt   + (size_t)(col0 + r) * K   + k0   + kk);
        }
        __syncthreads();   // prior iteration's LDS reads complete
        #pragma unroll
        for (int p = 0; p < 4; ++p) {
            int r = p * 32 + r_;
            *reinterpret_cast<uint4*>(&Xs[r * LROW + kk]) = xv[p];
            *reinterpret_cast<uint4*>(&Ws[r * LROW + kk]) = wvv[p];
        }
        __syncthreads();

        #pragma unroll
        for (int ks = 0; ks < 2; ++ks) {
            bf16x8 af[4], bfr[4];
            #pragma unroll
            for (int i = 0; i < 4; ++i) {
                int mrow = wm * 64 + i * 16 + (lane & 15);
                af[i]  = *reinterpret_cast<const bf16x8*>(&Xs[mrow * LROW + ks * 32 + (lane >> 4) * 8]);
                int ncol = wn * 64 + i * 16 + (lane & 15);
                bfr[i] = *reinterpret_cast<const bf16x8*>(&Ws[ncol * LROW + ks * 32 + (lane >> 4) * 8]);
            }
            #pragma unroll
            for (int i = 0; i < 4; ++i)
                #pragma unroll
                for (int j = 0; j < 4; ++j)
                    acc[i][j] = __builtin_amdgcn_mfma_f32_16x16x32_bf16(af[i], bfr[j], acc[i][j], 0, 0, 0);
        }
    }

    // C/D layout: col = lane&15, row = (lane>>4)*4 + reg
    #pragma unroll
    for (int i = 0; i < 4; ++i) {
        int gr0 = row0 + wm * 64 + i * 16 + ((lane >> 4) << 2);
        #pragma unroll
        for (int j = 0; j < 4; ++j) {
            int gc = col0 + wn * 64 + j * 16 + (lane & 15);
            #pragma unroll
            for (int r = 0; r < 4; ++r) {
                int gr = gr0 + r;
                if (gr >= Mstore) continue;
                float v = acc[i][j][r];
                if (flags & 1) v = lrelu(v);
                if (flags & 2) ((ushort*)out)[(size_t)gr * Nw + gc] = f2bf(v);
                else           ((float*) out)[(size_t)gr * Nw + gc] = v;
            }
        }
    }
}

// Fused: C = ef_tile @ We1_e (MFMA, K=64) into LDS, then edge message +
// bf16 atomic scatter. One block = 128 edges x 128 features (half of 256).
// Paired feature-half blocks are adjacent in grid.x (bid&1) so they share
// the ef tile in L2.
__global__ __launch_bounds__(256) void edge_fused(
    const ushort* __restrict__ efb,   // [Ep,64] bf16 (zero-padded)
    const ushort* __restrict__ Wet,   // [256,64] bf16, n-major
    const ushort* __restrict__ AB,    // [Np,512] bf16: row = [A(256) | B(256)]
    const int* __restrict__ src, const int* __restrict__ dst,
    ushort* __restrict__ H,           // [Np,256] bf16 accumulator
    int E)
{
    __shared__ ushort lds[128 * LROW * 2];   // staging, then aliased as C tile
    __shared__ int sd[256];                  // src[0..127] | dst[0..127]

    const int tid  = threadIdx.x;
    const int lane = tid & 63;
    const int wv   = tid >> 6;
    const int wm   = wv >> 1, wn = wv & 1;
    const int bid  = blockIdx.x;
    const int eb   = (bid >> 1) * 128;       // edge block base
    const int col0 = (bid & 1) * 128;        // feature half

    ushort* Xs = lds;                        // ef tile [128][LROW]
    ushort* Ws = lds + 128 * LROW;           // Wet half [128][LROW]

    // ---- stage ef tile + Wet half (K=64: one full row = 8 lanes x 16B) ----
    const int r_ = tid >> 3;                 // 0..31
    const int kk = (tid & 7) * 8;            // bf16 offset 0..56
    uint4 xv[4], wvv[4];
    #pragma unroll
    for (int p = 0; p < 4; ++p) {
        int r = p * 32 + r_;
        xv[p]  = *reinterpret_cast<const uint4*>(efb + (size_t)(eb + r) * 64 + kk);
        wvv[p] = *reinterpret_cast<const uint4*>(Wet + (size_t)(col0 + r) * 64 + kk);
    }
    if (tid < 128) sd[tid] = (eb + tid < E)         ? src[eb + tid]         : -1;
    else           sd[tid] = (eb + (tid - 128) < E) ? dst[eb + (tid - 128)] : -1;
    #pragma unroll
    for (int p = 0; p < 4; ++p) {
        int r = p * 32 + r_;
        *reinterpret_cast<uint4*>(&Xs[r * LROW + kk]) = xv[p];
        *reinterpret_cast<uint4*>(&Ws[r * LROW + kk]) = wvv[p];
    }
    __syncthreads();

    // ---- MFMA: Ct[128 edges x 128 features], K=64 ----
    f32x4 acc[4][4] = {};
    #pragma unroll
    for (int ks = 0; ks < 2; ++ks) {
        bf16x8 af[4], bfr[4];
        #pragma unroll
        for (int i = 0; i < 4; ++i) {
            int mrow = wm * 64 + i * 16 + (lane & 15);
            af[i]  = *reinterpret_cast<const bf16x8*>(&Xs[mrow * LROW + ks * 32 + (lane >> 4) * 8]);
            int ncol = wn * 64 + i * 16 + (lane & 15);
            bfr[i] = *reinterpret_cast<const bf16x8*>(&Ws[ncol * LROW + ks * 32 + (lane >> 4) * 8]);
        }
        #pragma unroll
        for (int i = 0; i < 4; ++i)
            #pragma unroll
            for (int j = 0; j < 4; ++j)
                acc[i][j] = __builtin_amdgcn_mfma_f32_16x16x32_bf16(af[i], bfr[j], acc[i][j], 0, 0, 0);
    }
    __syncthreads();           // staging reads done -> alias LDS as C tile

    // acc -> Cs bf16.  Cs pitch 132 (264B): for one (i,j,r) wave store, the
    // four (lane>>4) row-groups land on bank octets +0/+8/+16/+24 -> no conflict.
    ushort* Cs = lds;
    #pragma unroll
    for (int i = 0; i < 4; ++i) {
        int er0 = wm * 64 + i * 16 + ((lane >> 4) << 2);
        #pragma unroll
        for (int j = 0; j < 4; ++j) {
            int fc = wn * 64 + j * 16 + (lane & 15);
            #pragma unroll
            for (int r = 0; r < 4; ++r)
                Cs[(er0 + r) * CROW + fc] = f2bf(acc[i][j][r]);
        }
    }
    __syncthreads();

    // ---- edge pass: wave wv handles edge p*4+wv; lane = feature pair ----
    const int jj = lane * 2;                 // feature pair within this half
    const ushort* ABj = AB + col0 + jj;
    ushort* Hj = H + col0 + jj;
    for (int p = 0; p < 32; ++p) {
        int ee = p * 4 + wv;
        int s = sd[ee], d = sd[128 + ee];
        if (s < 0) continue;                 // wave-uniform (pad edges)
        ushort2 cv = *(const ushort2*)(&Cs[ee * CROW + jj]);
        ushort2 as = *(const ushort2*)(ABj + (size_t)s * 512);
        ushort2 bs = *(const ushort2*)(ABj + (size_t)s * 512 + 256);
        ushort2 ad = *(const ushort2*)(ABj + (size_t)d * 512);
        ushort2 bd = *(const ushort2*)(ABj + (size_t)d * 512 + 256);
        float c0 = bf2f(cv.x), c1 = bf2f(cv.y);
        ushort2 mf, mb;
        mf.x = f2bf(lrelu(bf2f(as.x) + bf2f(bd.x) + c0));
        mf.y = f2bf(lrelu(bf2f(as.y) + bf2f(bd.y) + c1));
        mb.x = f2bf(lrelu(bf2f(ad.x) + bf2f(bs.x) + c0));
        mb.y = f2bf(lrelu(bf2f(ad.y) + bf2f(bs.y) + c1));
        unsigned uf, ub;
        memcpy(&uf, &mf, 4); memcpy(&ub, &mb, 4);
        atomic_pk_add_bf16(Hj + (size_t)d * 256, uf);
        atomic_pk_add_bf16(Hj + (size_t)s * 256, ub);
    }
}

// float -> bf16 with zero padding; n_real, n_pad multiples of 4
__global__ __launch_bounds__(256) void cvt_pad(
    const float* __restrict__ x, ushort* __restrict__ y, size_t n_real, size_t n_pad)
{
    size_t i = ((size_t)blockIdx.x * 256 + threadIdx.x) * 4;
    if (i >= n_pad) return;
    ushort4 o;
    if (i < n_real) {
        float4 v = *(const float4*)(x + i);
        o.x = f2bf(v.x); o.y = f2bf(v.y); o.z = f2bf(v.z); o.w = f2bf(v.w);
    } else { o.x = 0; o.y = 0; o.z = 0; o.w = 0; }
    *(ushort4*)(y + i) = o;
}

// transpose + convert all weights to bf16 [N,K] layouts
__global__ __launch_bounds__(256) void wcvt(
    const float* __restrict__ We1, const float* __restrict__ We2,
    const float* __restrict__ Wn1, const float* __restrict__ Wn2,
    ushort* __restrict__ Wabt, ushort* __restrict__ Wet, ushort* __restrict__ We2t,
    ushort* __restrict__ Wn1t, ushort* __restrict__ Wn2t)
{
    int idx = blockIdx.x * 256 + threadIdx.x;
    switch (blockIdx.y) {
    case 0: if (idx < 256*128) { int n = idx >> 7, k = idx & 127; Wabt[idx]            = f2bf(We1[k * 256 + n]); } break;
    case 1: if (idx < 256*128) { int n = idx >> 7, k = idx & 127; Wabt[32768 + idx]    = f2bf(We1[(128 + k) * 256 + n]); } break;
    case 2: if (idx < 256*64)  { int n = idx >> 6, k = idx & 63;  Wet[idx]             = f2bf(We1[(256 + k) * 256 + n]); } break;
    case 3: if (idx < 128*256) { int n = idx >> 8, k = idx & 255; We2t[idx]            = f2bf(We2[k * 128 + n]); } break;
    case 4: if (idx < 256*256) { int n = idx >> 8, k = idx & 255; Wn1t[idx]            = f2bf(Wn1[k * 256 + n]); } break;
    case 5: if (idx < 128*256) { int n = idx >> 8, k = idx & 255; Wn2t[idx]            = f2bf(Wn2[k * 128 + n]); } break;
    }
}

extern "C" void kernel_launch(void* const* d_in, const int* in_sizes, int n_in,
                              void* d_out, int out_size, void* d_ws, size_t ws_size,
                              hipStream_t stream) {
    const float* nf  = (const float*)d_in[0];
    const float* ef  = (const float*)d_in[1];
    const int*   src = (const int*)d_in[2];
    const int*   dst = (const int*)d_in[3];
    const float* We1 = (const float*)d_in[4];
    const float* We2 = (const float*)d_in[5];
    const float* Wn1 = (const float*)d_in[6];
    const float* Wn2 = (const float*)d_in[7];
    float* out = (float*)d_out;

    const int  N  = in_sizes[0] / 128;            // 100000
    const int  E  = in_sizes[2];                  // 500000
    const int  Np = (N + 127) & ~127;             // 100096
    const long Ep = ((long)E + 127) & ~127L;      // 500096

    char* p = (char*)d_ws;
    auto alloc = [&](size_t bytes) { char* r = p; p += (bytes + 255) & ~(size_t)255; return r; };
    ushort* AB   = (ushort*)alloc((size_t)Np * 512 * 2);
    ushort* H    = (ushort*)alloc((size_t)Np * 256 * 2);   // bf16 accumulator
    ushort* nfb  = (ushort*)alloc((size_t)Np * 128 * 2);
    ushort* efb  = (ushort*)alloc((size_t)Ep * 64 * 2);
    ushort* Wabt = (ushort*)alloc(65536 * 2);
    ushort* Wet  = (ushort*)alloc(16384 * 2);
    ushort* We2t = (ushort*)alloc(32768 * 2);
    ushort* Wn1t = (ushort*)alloc(65536 * 2);
    ushort* Wn2t = (ushort*)alloc(32768 * 2);
    ushort* red = AB;                              // alias: AB dead after edge pass
    ushort* hid = AB + (size_t)Np * 128;

    dim3 blk(256);

    wcvt<<<dim3(256, 6), blk, 0, stream>>>(We1, We2, Wn1, Wn2, Wabt, Wet, We2t, Wn1t, Wn2t);
    cvt_pad<<<dim3((unsigned)((size_t)Np * 128 / 1024)), blk, 0, stream>>>(nf, nfb, (size_t)N * 128, (size_t)Np * 128);
    cvt_pad<<<dim3((unsigned)((size_t)Ep * 64 / 1024)), blk, 0, stream>>>(ef, efb, (size_t)E * 64, (size_t)Ep * 64);

    // AB = nf @ [We1_s | We1_d]
    gemm_bf16<<<dim3(Np / 128, 4), blk, 0, stream>>>(nfb, 128, nullptr, 0, Wabt, AB, 512, Np, 2);

    hipMemsetAsync(H, 0, (size_t)Np * 256 * 2, stream);

    // fused C-GEMM + edge scatter (C tile never leaves LDS)
    edge_fused<<<dim3((unsigned)(Ep / 128 * 2)), blk, 0, stream>>>(
        efb, Wet, AB, src, dst, H, E);

    // red = H @ We2   (H already bf16 -> no convert pass)
    gemm_bf16<<<dim3(Np / 128, 1), blk, 0, stream>>>(H, 256, nullptr, 0, We2t, red, 128, Np, 2);
    // hid = lrelu([nf|red] @ Wn1)
    gemm_bf16<<<dim3(Np / 128, 2), blk, 0, stream>>>(nfb, 128, red, 128, Wn1t, hid, 256, Np, 2 | 1);
    // out = hid @ Wn2  (fp32, guarded stores)
    gemm_bf16<<<dim3(Np / 128, 1), blk, 0, stream>>>(hid, 256, nullptr, 0, Wn2t, (void*)out, 128, N, 0);
}